// Round 11
// baseline (742.644 us; speedup 1.0000x reference)
//
#include <hip/hip_runtime.h>

#define N_NODES 50000
#define N_EDGES 800000
#define CH 128
#define N_GRAPHS 128
#define N_LAYERS 3
#define OUT_CH 16
#define BN_EPS 1e-5f
#define ZN N_NODES         // index of the all-zero pad row in Bh/Bz
#define NB 196             // dst>>8 buckets (256 dsts each)
#define BCAP 4608
#define PBCAP 8448         // padded bucket capacity, multiple of 16
#define EPB 4096
#define NTILES (N_NODES / 16)      // 3125 exact
#define SSTRIDE 20
// merged setup+bin block partition
#define BINB 196           // bin blocks (800000/4096)
#define CB 6250            // cast blocks (1.6M float4 / 256)
#define PB 388             // prep blocks

typedef unsigned short ushort_t;
typedef __attribute__((ext_vector_type(8))) short bf16x8;
typedef __attribute__((ext_vector_type(8))) unsigned short u16x8;
typedef __attribute__((ext_vector_type(4))) float f32x4;

__device__ inline ushort_t f2b(float f) {
    unsigned u = __float_as_uint(f);
    unsigned r = (u + 0x7fffu + ((u >> 16) & 1u)) >> 16;
    return (ushort_t)r;
}
__device__ inline float blo(unsigned u) { return __uint_as_float(u << 16); }
__device__ inline float bhi(unsigned u) { return __uint_as_float(u & 0xffff0000u); }

// -------- merged setup+bin: bin(196) | cast+zero(6250) | weight/epilogue prep(388) --------
// gcur (and the retirement counter) must be pre-zeroed via hipMemsetAsync.
__global__ __launch_bounds__(256) void setup_bin_kernel(
    const int* __restrict__ src, const int* __restrict__ dst,
    int* __restrict__ gcur, unsigned* __restrict__ gbuck,
    const float4* __restrict__ x, ushort4* __restrict__ xb, ushort4* __restrict__ xz,
    float* __restrict__ pooled,
    const float* __restrict__ W1, const float* __restrict__ W2, ushort_t* __restrict__ Wt,
    const float* __restrict__ b1, const float* __restrict__ b2,
    const float* __restrict__ gamma, const float* __restrict__ beta,
    const float* __restrict__ mean, const float* __restrict__ var,
    float* __restrict__ scale, float* __restrict__ shift) {
    int bid = blockIdx.x, t = threadIdx.x;
    if (bid < BINB) {
        // ---- edge binning: pack = src | (dst&255)<<16, bucket = dst>>8 ----
        __shared__ int lcnt[256];
        __shared__ int lpref[256];
        __shared__ int lpos[NB];
        __shared__ int lbase[NB];
        __shared__ unsigned stage[EPB];
        __shared__ unsigned char sbk[EPB];
        int e0 = bid * EPB;
        int nloc = N_EDGES - e0; if (nloc > EPB) nloc = EPB;

        lcnt[t] = 0;
        __syncthreads();

        int2 ed[16];
        const int4* s4 = (const int4*)(src + e0);
        const int4* d4 = (const int4*)(dst + e0);
        #pragma unroll
        for (int k = 0; k < 4; ++k) {
            int base = k * 1024 + t * 4;
            if (base + 3 < nloc) {
                int4 sv = s4[k * 256 + t];
                int4 dv = d4[k * 256 + t];
                ed[k * 4 + 0].x = sv.x; ed[k * 4 + 0].y = dv.x;
                ed[k * 4 + 1].x = sv.y; ed[k * 4 + 1].y = dv.y;
                ed[k * 4 + 2].x = sv.z; ed[k * 4 + 2].y = dv.z;
                ed[k * 4 + 3].x = sv.w; ed[k * 4 + 3].y = dv.w;
            } else {
                #pragma unroll
                for (int m = 0; m < 4; ++m) {
                    int i = base + m;
                    if (i < nloc) {
                        ed[k * 4 + m].x = src[e0 + i];
                        ed[k * 4 + m].y = dst[e0 + i];
                    } else ed[k * 4 + m].y = -1;
                }
            }
        }
        #pragma unroll
        for (int j = 0; j < 16; ++j)
            if (ed[j].y >= 0) atomicAdd(&lcnt[ed[j].y >> 8], 1);
        __syncthreads();
        int v = lcnt[t];
        lpref[t] = v;
        __syncthreads();
        for (int off = 1; off < 256; off <<= 1) {
            int y = (t >= off) ? lpref[t - off] : 0;
            __syncthreads();
            lpref[t] += y;
            __syncthreads();
        }
        int excl = lpref[t] - v;
        __syncthreads();
        lpref[t] = excl;
        if (t < NB) {
            lpos[t] = excl;
            lbase[t] = atomicAdd(&gcur[t], v);
        }
        __syncthreads();
        #pragma unroll
        for (int j = 0; j < 16; ++j) {
            if (ed[j].y >= 0) {
                int b = ed[j].y >> 8;
                int slot = atomicAdd(&lpos[b], 1);
                stage[slot] = (unsigned)ed[j].x | ((unsigned)(ed[j].y & 255) << 16);
                sbk[slot] = (unsigned char)b;
            }
        }
        __syncthreads();
        for (int i = t; i < nloc; i += 256) {
            int b = sbk[i];
            gbuck[(size_t)b * BCAP + lbase[b] + (i - lpref[b])] = stage[i];
        }
    } else if (bid < BINB + CB) {
        // ---- cast fp32 -> bf16 flat [N][128]; zero pooled; zero pad rows ----
        int i = (bid - BINB) * 256 + t;
        if (i < N_GRAPHS * CH) pooled[i] = 0.f;
        if (bid == BINB && t < 32) {
            ushort4 zz; zz.x = 0; zz.y = 0; zz.z = 0; zz.w = 0;
            xb[(size_t)ZN * 32 + t] = zz;      // zero row in Bh
            xz[(size_t)ZN * 32 + t] = zz;      // zero row in Bz
        }
        float4 v = x[i];               // CB*256 == n4 exactly
        ushort4 o;
        o.x = f2b(v.x); o.y = f2b(v.y); o.z = f2b(v.z); o.w = f2b(v.w);
        xb[i] = o;
    } else {
        // ---- weight fragments [ct][ks][lane][j] + scale/shift ----
        int i = (bid - BINB - CB) * 256 + t;
        if (i < 6 * CH * CH) {
            int mat = i >> 14, r = i & 16383;
            int j = r & 7, bb = r >> 3;
            int lane = bb & 63, cs = bb >> 6;
            int ct = cs >> 2, ks = cs & 3;
            int n = ct * 16 + (lane & 15);
            int k = ks * 32 + (lane >> 4) * 8 + j;
            const float* Wsrc = (mat < 3) ? (W1 + (size_t)mat * CH * CH)
                                          : (W2 + (size_t)(mat - 3) * CH * CH);
            Wt[i] = f2b(Wsrc[k * CH + n]);
        } else {
            int e = i - 6 * CH * CH;
            if (e >= 6 * CH) return;
            int mat = e / CH, c = e % CH;
            if (mat < 3) {
                scale[e] = 1.f;
                shift[e] = b1[mat * CH + c];
            } else {
                int l = mat - 3;
                float inv = gamma[l * CH + c] * rsqrtf(var[l * CH + c] + BN_EPS);
                scale[e] = inv;
                shift[e] = (b2[l * CH + c] - mean[l * CH + c]) * inv + beta[l * CH + c];
            }
        }
    }
}

// ---------------- per-bucket sort to PADDED CSR slots + per-tile LPT node order ------------
__global__ __launch_bounds__(256) void place_kernel(const int* __restrict__ gcur,
                                                    const unsigned* __restrict__ gbuck,
                                                    int* __restrict__ rowptr,
                                                    ushort_t* __restrict__ esrc,
                                                    unsigned char* __restrict__ nodeord) {
    __shared__ ushort_t ssrc[BCAP];
    __shared__ unsigned char sd[BCAP];
    __shared__ ushort_t outS[PBCAP];
    __shared__ unsigned char rndS[256];
    __shared__ int cnt[256], pref[256], cur[256];
    int b = blockIdx.x, t = threadIdx.x;
    cnt[t] = 0;
    __syncthreads();
    int nb = gcur[b];
    for (int i = t; i < nb; i += 256) {
        unsigned p = gbuck[(size_t)b * BCAP + i];
        ssrc[i] = (ushort_t)(p & 0xffffu);
        int dl = (p >> 16) & 0xff;
        sd[i] = (unsigned char)dl;
        atomicAdd(&cnt[dl], 1);
    }
    __syncthreads();
    int v = cnt[t];
    int pc = (v + 15) & ~15;            // padded degree
    pref[t] = pc;
    __syncthreads();
    for (int off = 1; off < 256; off <<= 1) {
        int y = (t >= off) ? pref[t - off] : 0;
        __syncthreads();
        pref[t] += y;
        __syncthreads();
    }
    int excl = pref[t] - pc;
    int total = pref[255];              // padded bucket size, <= PBCAP by construction
    __syncthreads();
    pref[t] = excl;
    cur[t] = 0;
    rndS[t] = (unsigned char)(pc >> 4);
    int idx = (b << 8) + t;
    if (idx < N_NODES)
        rowptr[idx] = (b * PBCAP + excl) | ((pc >> 4) << 24);
    __syncthreads();
    for (int i = t; i < total; i += 256) outS[i] = (ushort_t)ZN;   // pad fill
    if (t < 16) {
        // LPT order for tile t of this bucket: insertion-sort 16 local ids by rounds desc
        int base = t << 4;
        unsigned char ids[16];
        #pragma unroll
        for (int i = 0; i < 16; ++i) ids[i] = (unsigned char)i;
        for (int i = 1; i < 16; ++i) {
            unsigned char id = ids[i];
            int key = rndS[base + id];
            int j = i - 1;
            while (j >= 0 && (int)rndS[base + ids[j]] < key) { ids[j + 1] = ids[j]; --j; }
            ids[j + 1] = id;
        }
        #pragma unroll
        for (int i = 0; i < 16; ++i)
            nodeord[(b << 8) + base + i] = ids[i];
    }
    __syncthreads();
    for (int i = t; i < nb; i += 256) {
        int dl = sd[i];
        int p = pref[dl] + atomicAdd(&cur[dl], 1);
        outS[p] = ssrc[i];
    }
    __syncthreads();
    for (int i = t; i < total; i += 256)
        esrc[(size_t)b * PBCAP + i] = outS[i];
}

// ------- fused layer: LPT-paired exact-round agg + MLP1 + BN MLP2 (+pool +last-block cls) -
// Phase A/B/C identical to r10 (best measured). When do_pool: pooled atomics, then
// last-block retirement (threadfence + device counter) computes the classifier inline,
// eliminating the cls dispatch.
__global__ __launch_bounds__(512, 8) void layer_kernel(
    const unsigned* __restrict__ h2, const int* __restrict__ rowptr,
    const ushort_t* __restrict__ esrc, const unsigned char* __restrict__ nodeord,
    const ushort_t* __restrict__ Wf1, const ushort_t* __restrict__ Wf2,
    const float* __restrict__ shift1, const float* __restrict__ scale2,
    const float* __restrict__ shift2, ushort_t* __restrict__ hout,
    const int* __restrict__ batch, float* __restrict__ pooled, int do_pool,
    int* __restrict__ retire, const float* __restrict__ Wc,
    const float* __restrict__ bc, float* __restrict__ out) {
    __shared__ unsigned zt[16][68];            // z tile, u32 = 2 bf16; 68-dword row stride
    __shared__ ushort_t sS[CH * SSTRIDE];      // mid, transposed [k][row(16)+4 pad]
    __shared__ int slast;

    int t = threadIdx.x;
    int wave = t >> 6, lane = t & 63;
    int quad = lane >> 4, l16 = lane & 15;
    int row0 = blockIdx.x * 16;

    // ---- phase A: LPT-paired aggregate, exact full-16 rounds per node ----
    {
        int oa = __builtin_amdgcn_readfirstlane(nodeord[row0 + wave]);
        int ob = __builtin_amdgcn_readfirstlane(nodeord[row0 + 15 - wave]);
        #pragma unroll
        for (int nn = 0; nn < 2; ++nn) {
            int lo = (nn == 0) ? oa : ob;
            int node = row0 + lo;
            unsigned self = h2[(size_t)node * 64 + lane];
            float ax = blo(self), ay = bhi(self);
            int pr = __builtin_amdgcn_readfirstlane(rowptr[node]);
            int e = pr & 0xFFFFFF;
            int rounds = (int)((unsigned)pr >> 24);
            for (int r = 0; r < rounds; ++r, e += 16) {
                u16x8 i0 = *(const u16x8*)(esrc + e);
                u16x8 i1 = *(const u16x8*)(esrc + e + 8);
                unsigned u[16];
                #pragma unroll
                for (int j = 0; j < 8; ++j)
                    u[j] = h2[(size_t)i0[j] * 64 + lane];
                #pragma unroll
                for (int j = 0; j < 8; ++j)
                    u[8 + j] = h2[(size_t)i1[j] * 64 + lane];
                #pragma unroll
                for (int j = 0; j < 16; ++j) { ax += blo(u[j]); ay += bhi(u[j]); }
            }
            zt[lo][lane] = ((unsigned)f2b(ay) << 16) | (unsigned)f2b(ax);
        }
    }
    __syncthreads();

    // ---- phase B: gemm1 col-tile ct = wave; mid -> sS (transposed) ----
    {
        bf16x8 af[4];
        #pragma unroll
        for (int ks = 0; ks < 4; ++ks)
            af[ks] = *(const bf16x8*)((const ushort_t*)&zt[l16][0] + ks * 32 + quad * 8);
        bf16x8 w1[4];
        #pragma unroll
        for (int ks = 0; ks < 4; ++ks)
            w1[ks] = *(const bf16x8*)(Wf1 + ((size_t)(wave * 4 + ks) * 64 + lane) * 8);
        f32x4 acc = (f32x4){0.f, 0.f, 0.f, 0.f};
        #pragma unroll
        for (int ks = 0; ks < 4; ++ks)
            acc = __builtin_amdgcn_mfma_f32_16x16x32_bf16(af[ks], w1[ks], acc, 0, 0, 0);
        int k = wave * 16 + l16;
        float sh = shift1[k];
        uint2 p;
        p.x = ((unsigned)f2b(fmaxf(acc[1] + sh, 0.f)) << 16)
            |  (unsigned)f2b(fmaxf(acc[0] + sh, 0.f));
        p.y = ((unsigned)f2b(fmaxf(acc[3] + sh, 0.f)) << 16)
            |  (unsigned)f2b(fmaxf(acc[2] + sh, 0.f));
        *(uint2*)&sS[k * SSTRIDE + quad * 4] = p;
    }
    __syncthreads();

    // ---- phase C: gemm2 col-tile ct = wave; BN-folded epilogue -> hout or pooled ----
    {
        bf16x8 af2[4];
        #pragma unroll
        for (int ks = 0; ks < 4; ++ks)
            #pragma unroll
            for (int j = 0; j < 8; ++j)
                af2[ks][j] = (short)sS[(ks * 32 + quad * 8 + j) * SSTRIDE + l16];
        bf16x8 w2[4];
        #pragma unroll
        for (int ks = 0; ks < 4; ++ks)
            w2[ks] = *(const bf16x8*)(Wf2 + ((size_t)(wave * 4 + ks) * 64 + lane) * 8);
        f32x4 acc = (f32x4){0.f, 0.f, 0.f, 0.f};
        #pragma unroll
        for (int ks = 0; ks < 4; ++ks)
            acc = __builtin_amdgcn_mfma_f32_16x16x32_bf16(af2[ks], w2[ks], acc, 0, 0, 0);
        int col = wave * 16 + l16;
        float sc = scale2[col], sh = shift2[col];
        float hv[4];
        #pragma unroll
        for (int r = 0; r < 4; ++r)
            hv[r] = fmaxf(acc[r] * sc + sh, 0.f);
        if (!do_pool) {
            #pragma unroll
            for (int r = 0; r < 4; ++r) {
                int row = row0 + quad * 4 + r;
                hout[(size_t)row * CH + col] = f2b(hv[r]);
            }
        } else {
            int g0 = batch[row0], g15 = batch[row0 + 15];
            if (g0 == g15) {
                float s = hv[0] + hv[1] + hv[2] + hv[3];
                s += __shfl_xor(s, 16);
                s += __shfl_xor(s, 32);
                if (quad == 0) atomicAdd(&pooled[g0 * CH + col], s);
            } else {
                #pragma unroll
                for (int r = 0; r < 4; ++r) {
                    int row = row0 + quad * 4 + r;
                    atomicAdd(&pooled[batch[row] * CH + col], hv[r]);
                }
            }
            // ---- last-block retirement: inline classifier ----
            __threadfence();
            __syncthreads();
            if (t == 0) {
                int old = atomicAdd(retire, 1);
                slast = (old == NTILES - 1) ? 1 : 0;
            }
            __syncthreads();
            if (slast) {
                __threadfence();
                for (int i = t; i < N_GRAPHS * OUT_CH; i += 512) {
                    int g = i >> 4, o = i & (OUT_CH - 1);
                    float s = bc[o];
                    #pragma unroll 4
                    for (int k = 0; k < CH; ++k)
                        s += pooled[g * CH + k] * Wc[k * OUT_CH + o];
                    out[i] = s;
                }
            }
        }
    }
}

// ---------------- launch ----------------
extern "C" void kernel_launch(void* const* d_in, const int* in_sizes, int n_in,
                              void* d_out, int out_size, void* d_ws, size_t ws_size,
                              hipStream_t stream) {
    const float* x     = (const float*)d_in[0];
    const int*   eidx  = (const int*)d_in[1];
    const int*   batch = (const int*)d_in[2];
    const float* W1    = (const float*)d_in[3];
    const float* b1    = (const float*)d_in[4];
    const float* W2    = (const float*)d_in[5];
    const float* b2    = (const float*)d_in[6];
    const float* gamma = (const float*)d_in[7];
    const float* beta  = (const float*)d_in[8];
    const float* mean  = (const float*)d_in[9];
    const float* var   = (const float*)d_in[10];
    const float* Wc    = (const float*)d_in[11];
    const float* bc    = (const float*)d_in[12];
    float* out = (float*)d_out;

    const int* src = eidx;
    const int* dst = eidx + N_EDGES;

    char* w = (char*)d_ws;
    size_t off = 0;
    auto alloc = [&](size_t bytes) { void* p = w + off; off += (bytes + 255) & ~(size_t)255; return p; };
    int*      gcur   = (int*)alloc((NB + 1) * 4);   // [NB] = retirement counter
    unsigned* gbuck  = (unsigned*)alloc((size_t)NB * BCAP * 4);
    int*      rowptr = (int*)alloc(N_NODES * 4);
    ushort_t* esrc   = (ushort_t*)alloc((size_t)NB * PBCAP * 2);
    unsigned char* nodeord = (unsigned char*)alloc((size_t)NB * 256);
    ushort_t* Bh     = (ushort_t*)alloc((size_t)(N_NODES + 1) * CH * 2);  // +1 zero pad row
    ushort_t* Bz     = (ushort_t*)alloc((size_t)(N_NODES + 1) * CH * 2);  // +1 zero pad row
    ushort_t* Wt     = (ushort_t*)alloc((size_t)6 * CH * CH * 2);
    float*    scale  = (float*)alloc(6 * CH * 4);
    float*    shift  = (float*)alloc(6 * CH * 4);
    float*    pooled = (float*)alloc(N_GRAPHS * CH * 4);
    (void)ws_size; (void)n_in; (void)in_sizes; (void)out_size;

    int* retire = gcur + NB;

    hipMemsetAsync(gcur, 0, (NB + 1) * 4, stream);
    setup_bin_kernel<<<BINB + CB + PB, 256, 0, stream>>>(
        src, dst, gcur, gbuck,
        (const float4*)x, (ushort4*)Bh, (ushort4*)Bz, pooled,
        W1, W2, Wt, b1, b2, gamma, beta, mean, var, scale, shift);
    place_kernel<<<NB, 256, 0, stream>>>(gcur, gbuck, rowptr, esrc, nodeord);

    ushort_t* bufA = Bh;
    ushort_t* bufB = Bz;
    for (int i = 0; i < N_LAYERS; ++i) {
        int last = (i == N_LAYERS - 1);
        layer_kernel<<<NTILES, 512, 0, stream>>>((const unsigned*)bufA, rowptr, esrc, nodeord,
                                                 Wt + (size_t)i * CH * CH,
                                                 Wt + (size_t)(3 + i) * CH * CH,
                                                 shift + i * CH,
                                                 scale + (3 + i) * CH,
                                                 shift + (3 + i) * CH,
                                                 bufB, batch, pooled, last,
                                                 retire, Wc, bc, out);
        ushort_t* tmp = bufA; bufA = bufB; bufB = tmp;
    }
}

// Round 12
// 218.968 us; speedup vs baseline: 3.3916x; 3.3916x over previous
//
#include <hip/hip_runtime.h>

#define N_NODES 50000
#define N_EDGES 800000
#define CH 128
#define N_GRAPHS 128
#define N_LAYERS 3
#define OUT_CH 16
#define BN_EPS 1e-5f
#define ZN N_NODES         // index of the all-zero pad row in Bh/Bz
#define NB 196             // dst>>8 buckets (256 dsts each)
#define BCAP 4608
#define PBCAP 8448         // padded bucket capacity, multiple of 16
#define EPB 4096
#define NTILES (N_NODES / 16)      // 3125 exact
#define SSTRIDE 20
// merged setup+bin block partition
#define BINB 196           // bin blocks (800000/4096)
#define CB 6250            // cast blocks (1.6M float4 / 256)
#define PB 388             // prep blocks

typedef unsigned short ushort_t;
typedef __attribute__((ext_vector_type(8))) short bf16x8;
typedef __attribute__((ext_vector_type(8))) unsigned short u16x8;
typedef __attribute__((ext_vector_type(4))) float f32x4;

__device__ inline ushort_t f2b(float f) {
    unsigned u = __float_as_uint(f);
    unsigned r = (u + 0x7fffu + ((u >> 16) & 1u)) >> 16;
    return (ushort_t)r;
}
__device__ inline float blo(unsigned u) { return __uint_as_float(u << 16); }
__device__ inline float bhi(unsigned u) { return __uint_as_float(u & 0xffff0000u); }

// -------- merged setup+bin: bin(196) | cast+zero(6250) | weight/epilogue prep(388) --------
// gcur must be pre-zeroed via hipMemsetAsync (bin blocks atomicAdd it concurrently).
__global__ __launch_bounds__(256) void setup_bin_kernel(
    const int* __restrict__ src, const int* __restrict__ dst,
    int* __restrict__ gcur, unsigned* __restrict__ gbuck,
    const float4* __restrict__ x, ushort4* __restrict__ xb, ushort4* __restrict__ xz,
    float* __restrict__ pooled,
    const float* __restrict__ W1, const float* __restrict__ W2, ushort_t* __restrict__ Wt,
    const float* __restrict__ b1, const float* __restrict__ b2,
    const float* __restrict__ gamma, const float* __restrict__ beta,
    const float* __restrict__ mean, const float* __restrict__ var,
    float* __restrict__ scale, float* __restrict__ shift) {
    int bid = blockIdx.x, t = threadIdx.x;
    if (bid < BINB) {
        // ---- edge binning: pack = src | (dst&255)<<16, bucket = dst>>8 ----
        __shared__ int lcnt[256];
        __shared__ int lpref[256];
        __shared__ int lpos[NB];
        __shared__ int lbase[NB];
        __shared__ unsigned stage[EPB];
        __shared__ unsigned char sbk[EPB];
        int e0 = bid * EPB;
        int nloc = N_EDGES - e0; if (nloc > EPB) nloc = EPB;

        lcnt[t] = 0;
        __syncthreads();

        int2 ed[16];
        const int4* s4 = (const int4*)(src + e0);
        const int4* d4 = (const int4*)(dst + e0);
        #pragma unroll
        for (int k = 0; k < 4; ++k) {
            int base = k * 1024 + t * 4;
            if (base + 3 < nloc) {
                int4 sv = s4[k * 256 + t];
                int4 dv = d4[k * 256 + t];
                ed[k * 4 + 0].x = sv.x; ed[k * 4 + 0].y = dv.x;
                ed[k * 4 + 1].x = sv.y; ed[k * 4 + 1].y = dv.y;
                ed[k * 4 + 2].x = sv.z; ed[k * 4 + 2].y = dv.z;
                ed[k * 4 + 3].x = sv.w; ed[k * 4 + 3].y = dv.w;
            } else {
                #pragma unroll
                for (int m = 0; m < 4; ++m) {
                    int i = base + m;
                    if (i < nloc) {
                        ed[k * 4 + m].x = src[e0 + i];
                        ed[k * 4 + m].y = dst[e0 + i];
                    } else ed[k * 4 + m].y = -1;
                }
            }
        }
        #pragma unroll
        for (int j = 0; j < 16; ++j)
            if (ed[j].y >= 0) atomicAdd(&lcnt[ed[j].y >> 8], 1);
        __syncthreads();
        int v = lcnt[t];
        lpref[t] = v;
        __syncthreads();
        for (int off = 1; off < 256; off <<= 1) {
            int y = (t >= off) ? lpref[t - off] : 0;
            __syncthreads();
            lpref[t] += y;
            __syncthreads();
        }
        int excl = lpref[t] - v;
        __syncthreads();
        lpref[t] = excl;
        if (t < NB) {
            lpos[t] = excl;
            lbase[t] = atomicAdd(&gcur[t], v);
        }
        __syncthreads();
        #pragma unroll
        for (int j = 0; j < 16; ++j) {
            if (ed[j].y >= 0) {
                int b = ed[j].y >> 8;
                int slot = atomicAdd(&lpos[b], 1);
                stage[slot] = (unsigned)ed[j].x | ((unsigned)(ed[j].y & 255) << 16);
                sbk[slot] = (unsigned char)b;
            }
        }
        __syncthreads();
        for (int i = t; i < nloc; i += 256) {
            int b = sbk[i];
            gbuck[(size_t)b * BCAP + lbase[b] + (i - lpref[b])] = stage[i];
        }
    } else if (bid < BINB + CB) {
        // ---- cast fp32 -> bf16 flat [N][128]; zero pooled; zero pad rows ----
        int i = (bid - BINB) * 256 + t;
        if (i < N_GRAPHS * CH) pooled[i] = 0.f;
        if (bid == BINB && t < 32) {
            ushort4 zz; zz.x = 0; zz.y = 0; zz.z = 0; zz.w = 0;
            xb[(size_t)ZN * 32 + t] = zz;      // zero row in Bh
            xz[(size_t)ZN * 32 + t] = zz;      // zero row in Bz
        }
        float4 v = x[i];               // CB*256 == n4 exactly
        ushort4 o;
        o.x = f2b(v.x); o.y = f2b(v.y); o.z = f2b(v.z); o.w = f2b(v.w);
        xb[i] = o;
    } else {
        // ---- weight fragments [ct][ks][lane][j] + scale/shift ----
        int i = (bid - BINB - CB) * 256 + t;
        if (i < 6 * CH * CH) {
            int mat = i >> 14, r = i & 16383;
            int j = r & 7, bb = r >> 3;
            int lane = bb & 63, cs = bb >> 6;
            int ct = cs >> 2, ks = cs & 3;
            int n = ct * 16 + (lane & 15);
            int k = ks * 32 + (lane >> 4) * 8 + j;
            const float* Wsrc = (mat < 3) ? (W1 + (size_t)mat * CH * CH)
                                          : (W2 + (size_t)(mat - 3) * CH * CH);
            Wt[i] = f2b(Wsrc[k * CH + n]);
        } else {
            int e = i - 6 * CH * CH;
            if (e >= 6 * CH) return;
            int mat = e / CH, c = e % CH;
            if (mat < 3) {
                scale[e] = 1.f;
                shift[e] = b1[mat * CH + c];
            } else {
                int l = mat - 3;
                float inv = gamma[l * CH + c] * rsqrtf(var[l * CH + c] + BN_EPS);
                scale[e] = inv;
                shift[e] = (b2[l * CH + c] - mean[l * CH + c]) * inv + beta[l * CH + c];
            }
        }
    }
}

// ---------------- per-bucket sort to PADDED CSR slots + per-tile LPT node order ------------
__global__ __launch_bounds__(256) void place_kernel(const int* __restrict__ gcur,
                                                    const unsigned* __restrict__ gbuck,
                                                    int* __restrict__ rowptr,
                                                    ushort_t* __restrict__ esrc,
                                                    unsigned char* __restrict__ nodeord) {
    __shared__ ushort_t ssrc[BCAP];
    __shared__ unsigned char sd[BCAP];
    __shared__ ushort_t outS[PBCAP];
    __shared__ unsigned char rndS[256];
    __shared__ int cnt[256], pref[256], cur[256];
    int b = blockIdx.x, t = threadIdx.x;
    cnt[t] = 0;
    __syncthreads();
    int nb = gcur[b];
    for (int i = t; i < nb; i += 256) {
        unsigned p = gbuck[(size_t)b * BCAP + i];
        ssrc[i] = (ushort_t)(p & 0xffffu);
        int dl = (p >> 16) & 0xff;
        sd[i] = (unsigned char)dl;
        atomicAdd(&cnt[dl], 1);
    }
    __syncthreads();
    int v = cnt[t];
    int pc = (v + 15) & ~15;            // padded degree
    pref[t] = pc;
    __syncthreads();
    for (int off = 1; off < 256; off <<= 1) {
        int y = (t >= off) ? pref[t - off] : 0;
        __syncthreads();
        pref[t] += y;
        __syncthreads();
    }
    int excl = pref[t] - pc;
    int total = pref[255];              // padded bucket size, <= PBCAP by construction
    __syncthreads();
    pref[t] = excl;
    cur[t] = 0;
    rndS[t] = (unsigned char)(pc >> 4);
    int idx = (b << 8) + t;
    if (idx < N_NODES)
        rowptr[idx] = (b * PBCAP + excl) | ((pc >> 4) << 24);
    __syncthreads();
    for (int i = t; i < total; i += 256) outS[i] = (ushort_t)ZN;   // pad fill
    if (t < 16) {
        // LPT order for tile t of this bucket: insertion-sort 16 local ids by rounds desc
        int base = t << 4;
        unsigned char ids[16];
        #pragma unroll
        for (int i = 0; i < 16; ++i) ids[i] = (unsigned char)i;
        for (int i = 1; i < 16; ++i) {
            unsigned char id = ids[i];
            int key = rndS[base + id];
            int j = i - 1;
            while (j >= 0 && (int)rndS[base + ids[j]] < key) { ids[j + 1] = ids[j]; --j; }
            ids[j + 1] = id;
        }
        #pragma unroll
        for (int i = 0; i < 16; ++i)
            nodeord[(b << 8) + base + i] = ids[i];
    }
    __syncthreads();
    for (int i = t; i < nb; i += 256) {
        int dl = sd[i];
        int p = pref[dl] + atomicAdd(&cur[dl], 1);
        outS[p] = ssrc[i];
    }
    __syncthreads();
    for (int i = t; i < total; i += 256)
        esrc[(size_t)b * PBCAP + i] = outS[i];
}

// ------- fused layer: LPT-paired exact-round agg + MLP1 + BN MLP2 (+pool fusion) ----------
// r10 structure (best measured) + weight register prefetch: w1 loaded BEFORE phase A and
// w2 at the top of phase B, so both L2 weight-load latencies hide under prior phases
// (loads stay in flight across s_barrier). Live-VGPR budget: A ~48, B ~56 (cap 64).
__global__ __launch_bounds__(512, 8) void layer_kernel(
    const unsigned* __restrict__ h2, const int* __restrict__ rowptr,
    const ushort_t* __restrict__ esrc, const unsigned char* __restrict__ nodeord,
    const ushort_t* __restrict__ Wf1, const ushort_t* __restrict__ Wf2,
    const float* __restrict__ shift1, const float* __restrict__ scale2,
    const float* __restrict__ shift2, ushort_t* __restrict__ hout,
    const int* __restrict__ batch, float* __restrict__ pooled, int do_pool) {
    __shared__ unsigned zt[16][68];            // z tile, u32 = 2 bf16; 68-dword row stride
    __shared__ ushort_t sS[CH * SSTRIDE];      // mid, transposed [k][row(16)+4 pad]

    int t = threadIdx.x;
    int wave = t >> 6, lane = t & 63;
    int quad = lane >> 4, l16 = lane & 15;
    int row0 = blockIdx.x * 16;

    // ---- prefetch gemm1 weights (independent of phase A; hides L2 latency) ----
    bf16x8 w1[4];
    #pragma unroll
    for (int ks = 0; ks < 4; ++ks)
        w1[ks] = *(const bf16x8*)(Wf1 + ((size_t)(wave * 4 + ks) * 64 + lane) * 8);

    // ---- phase A: LPT-paired aggregate, exact full-16 rounds per node ----
    {
        int oa = __builtin_amdgcn_readfirstlane(nodeord[row0 + wave]);
        int ob = __builtin_amdgcn_readfirstlane(nodeord[row0 + 15 - wave]);
        #pragma unroll
        for (int nn = 0; nn < 2; ++nn) {
            int lo = (nn == 0) ? oa : ob;
            int node = row0 + lo;
            unsigned self = h2[(size_t)node * 64 + lane];
            float ax = blo(self), ay = bhi(self);
            int pr = __builtin_amdgcn_readfirstlane(rowptr[node]);
            int e = pr & 0xFFFFFF;
            int rounds = (int)((unsigned)pr >> 24);
            for (int r = 0; r < rounds; ++r, e += 16) {
                u16x8 i0 = *(const u16x8*)(esrc + e);
                u16x8 i1 = *(const u16x8*)(esrc + e + 8);
                unsigned u[16];
                #pragma unroll
                for (int j = 0; j < 8; ++j)
                    u[j] = h2[(size_t)i0[j] * 64 + lane];
                #pragma unroll
                for (int j = 0; j < 8; ++j)
                    u[8 + j] = h2[(size_t)i1[j] * 64 + lane];
                #pragma unroll
                for (int j = 0; j < 16; ++j) { ax += blo(u[j]); ay += bhi(u[j]); }
            }
            zt[lo][lane] = ((unsigned)f2b(ay) << 16) | (unsigned)f2b(ax);
        }
    }
    __syncthreads();

    // ---- phase B: gemm1 col-tile ct = wave; mid -> sS; prefetch w2 under it ----
    bf16x8 w2[4];
    #pragma unroll
    for (int ks = 0; ks < 4; ++ks)
        w2[ks] = *(const bf16x8*)(Wf2 + ((size_t)(wave * 4 + ks) * 64 + lane) * 8);
    {
        bf16x8 af[4];
        #pragma unroll
        for (int ks = 0; ks < 4; ++ks)
            af[ks] = *(const bf16x8*)((const ushort_t*)&zt[l16][0] + ks * 32 + quad * 8);
        f32x4 acc = (f32x4){0.f, 0.f, 0.f, 0.f};
        #pragma unroll
        for (int ks = 0; ks < 4; ++ks)
            acc = __builtin_amdgcn_mfma_f32_16x16x32_bf16(af[ks], w1[ks], acc, 0, 0, 0);
        int k = wave * 16 + l16;
        float sh = shift1[k];
        uint2 p;
        p.x = ((unsigned)f2b(fmaxf(acc[1] + sh, 0.f)) << 16)
            |  (unsigned)f2b(fmaxf(acc[0] + sh, 0.f));
        p.y = ((unsigned)f2b(fmaxf(acc[3] + sh, 0.f)) << 16)
            |  (unsigned)f2b(fmaxf(acc[2] + sh, 0.f));
        *(uint2*)&sS[k * SSTRIDE + quad * 4] = p;
    }
    __syncthreads();

    // ---- phase C: gemm2 col-tile ct = wave; BN-folded epilogue -> hout or pooled ----
    {
        bf16x8 af2[4];
        #pragma unroll
        for (int ks = 0; ks < 4; ++ks)
            #pragma unroll
            for (int j = 0; j < 8; ++j)
                af2[ks][j] = (short)sS[(ks * 32 + quad * 8 + j) * SSTRIDE + l16];
        f32x4 acc = (f32x4){0.f, 0.f, 0.f, 0.f};
        #pragma unroll
        for (int ks = 0; ks < 4; ++ks)
            acc = __builtin_amdgcn_mfma_f32_16x16x32_bf16(af2[ks], w2[ks], acc, 0, 0, 0);
        int col = wave * 16 + l16;
        float sc = scale2[col], sh = shift2[col];
        float hv[4];
        #pragma unroll
        for (int r = 0; r < 4; ++r)
            hv[r] = fmaxf(acc[r] * sc + sh, 0.f);
        if (!do_pool) {
            #pragma unroll
            for (int r = 0; r < 4; ++r) {
                int row = row0 + quad * 4 + r;
                hout[(size_t)row * CH + col] = f2b(hv[r]);
            }
        } else {
            int g0 = batch[row0], g15 = batch[row0 + 15];
            if (g0 == g15) {
                float s = hv[0] + hv[1] + hv[2] + hv[3];
                s += __shfl_xor(s, 16);
                s += __shfl_xor(s, 32);
                if (quad == 0) atomicAdd(&pooled[g0 * CH + col], s);
            } else {
                #pragma unroll
                for (int r = 0; r < 4; ++r) {
                    int row = row0 + quad * 4 + r;
                    atomicAdd(&pooled[batch[row] * CH + col], hv[r]);
                }
            }
        }
    }
}

// ---------------- classifier: out = pooled @ Wc + bc ----------------
__global__ __launch_bounds__(256) void cls_kernel(const float* __restrict__ pooled,
                                                  const float* __restrict__ Wc,
                                                  const float* __restrict__ bc,
                                                  float* __restrict__ out) {
    int i = blockIdx.x * blockDim.x + threadIdx.x;
    if (i >= N_GRAPHS * OUT_CH) return;
    int g = i / OUT_CH, o = i % OUT_CH;
    float s = bc[o];
    for (int k = 0; k < CH; ++k) s += pooled[g * CH + k] * Wc[k * OUT_CH + o];
    out[i] = s;
}

// ---------------- launch ----------------
extern "C" void kernel_launch(void* const* d_in, const int* in_sizes, int n_in,
                              void* d_out, int out_size, void* d_ws, size_t ws_size,
                              hipStream_t stream) {
    const float* x     = (const float*)d_in[0];
    const int*   eidx  = (const int*)d_in[1];
    const int*   batch = (const int*)d_in[2];
    const float* W1    = (const float*)d_in[3];
    const float* b1    = (const float*)d_in[4];
    const float* W2    = (const float*)d_in[5];
    const float* b2    = (const float*)d_in[6];
    const float* gamma = (const float*)d_in[7];
    const float* beta  = (const float*)d_in[8];
    const float* mean  = (const float*)d_in[9];
    const float* var   = (const float*)d_in[10];
    const float* Wc    = (const float*)d_in[11];
    const float* bc    = (const float*)d_in[12];
    float* out = (float*)d_out;

    const int* src = eidx;
    const int* dst = eidx + N_EDGES;

    char* w = (char*)d_ws;
    size_t off = 0;
    auto alloc = [&](size_t bytes) { void* p = w + off; off += (bytes + 255) & ~(size_t)255; return p; };
    int*      gcur   = (int*)alloc(NB * 4);
    unsigned* gbuck  = (unsigned*)alloc((size_t)NB * BCAP * 4);
    int*      rowptr = (int*)alloc(N_NODES * 4);
    ushort_t* esrc   = (ushort_t*)alloc((size_t)NB * PBCAP * 2);
    unsigned char* nodeord = (unsigned char*)alloc((size_t)NB * 256);
    ushort_t* Bh     = (ushort_t*)alloc((size_t)(N_NODES + 1) * CH * 2);  // +1 zero pad row
    ushort_t* Bz     = (ushort_t*)alloc((size_t)(N_NODES + 1) * CH * 2);  // +1 zero pad row
    ushort_t* Wt     = (ushort_t*)alloc((size_t)6 * CH * CH * 2);
    float*    scale  = (float*)alloc(6 * CH * 4);
    float*    shift  = (float*)alloc(6 * CH * 4);
    float*    pooled = (float*)alloc(N_GRAPHS * CH * 4);
    (void)ws_size; (void)n_in; (void)in_sizes; (void)out_size;

    hipMemsetAsync(gcur, 0, NB * 4, stream);
    setup_bin_kernel<<<BINB + CB + PB, 256, 0, stream>>>(
        src, dst, gcur, gbuck,
        (const float4*)x, (ushort4*)Bh, (ushort4*)Bz, pooled,
        W1, W2, Wt, b1, b2, gamma, beta, mean, var, scale, shift);
    place_kernel<<<NB, 256, 0, stream>>>(gcur, gbuck, rowptr, esrc, nodeord);

    ushort_t* bufA = Bh;
    ushort_t* bufB = Bz;
    for (int i = 0; i < N_LAYERS; ++i) {
        int last = (i == N_LAYERS - 1);
        layer_kernel<<<NTILES, 512, 0, stream>>>((const unsigned*)bufA, rowptr, esrc, nodeord,
                                                 Wt + (size_t)i * CH * CH,
                                                 Wt + (size_t)(3 + i) * CH * CH,
                                                 shift + i * CH,
                                                 scale + (3 + i) * CH,
                                                 shift + (3 + i) * CH,
                                                 bufB, batch, pooled, last);
        ushort_t* tmp = bufA; bufA = bufB; bufB = tmp;
    }

    cls_kernel<<<(N_GRAPHS * OUT_CH + 255) / 256, 256, 0, stream>>>(pooled, Wc, bc, out);
}